// Round 3
// baseline (453.528 us; speedup 1.0000x reference)
//
#include <hip/hip_runtime.h>

constexpr int NL    = 48;
constexpr int SEQ   = 1024;
constexpr int BATCH = 512;

// DPP row_ror:N (rotate within each 16-lane row) -- pure VALU cross-lane,
// ~4-8 cy latency vs ~120 cy for an LDS round trip.
template<int N>
__device__ __forceinline__ float rrf(float x) {
    if constexpr (N == 0) return x;
    else {
        int xi = __float_as_int(x);
        return __int_as_float(
            __builtin_amdgcn_update_dpp(xi, xi, 0x120 | N, 0xF, 0xF, false));
    }
}
template<int N>
__device__ __forceinline__ unsigned rru(unsigned x) {
    if constexpr (N == 0) return x;
    else return (unsigned)
        __builtin_amdgcn_update_dpp((int)x, (int)x, 0x120 | N, 0xF, 0xF, false);
}

// 3-op full-wave spread via gfx950 permlane swaps (VALU): from per-lane x
// produce 4 streams whose 16-lane rows each hold a replicated 16-value slice
// of x.  Nominal layout: c = x[i&15], d = x[16+(i&15)], e = x[32+(i&15)],
// f = x[48+(i&15)].  NOTE: correctness does NOT depend on this nominal
// layout being exactly right -- the E coefficients are derived by pushing
// the lane index through this same network (see EPREP), so any consistent
// permutation works.
__device__ __forceinline__ void spread4(unsigned x,
        unsigned &c, unsigned &d, unsigned &e, unsigned &f) {
    auto rA = __builtin_amdgcn_permlane32_swap(x, x, false, false);
    auto rc = __builtin_amdgcn_permlane16_swap(rA[0], rA[0], false, false);
    auto re = __builtin_amdgcn_permlane16_swap(rA[1], rA[1], false, false);
    c = rc[0]; d = rc[1]; e = re[0]; f = re[1];
}

// Dot-product partial updates: rotation N of streams c/d/e (and f when live)
// against the index-matched coefficient tables.  DPP folds into the fmac
// (v_fmac_f32_dpp) or costs one v_mov_dpp -- either way VALU-pipe only.
#define RF3(N_, pa_, pb_, pc_)                                                \
    pa_ = fmaf(rrf<N_>(c_), EA[N_], pa_);                                     \
    pb_ = fmaf(rrf<N_>(d_), EB[N_], pb_);                                     \
    pc_ = fmaf(rrf<N_>(e_), EC[N_], pc_);
#define RFF(N_, pd_) pd_ = fmaf(rrf<N_>(f_), ED[N_], pd_);

// One forward step, entirely in the VALU: 3 permlane + 48 rotated FMAs.
// No LDS, no SGPR broadcast, no DS pipe anywhere in the chain.
// RN_: renorm max over the pre-step v taken from the spread streams
// (junk lanes carry exact duplicates of v[47] -- never affect the max),
// reduced by a 4-deep row_ror max butterfly; rm_ folded into both mask
// paths exactly as before; S += log(max).
#define CRF_STEP(T_, SLOT_, RN_) do {                                         \
    float ee_ = __expf(embuf[SLOT_]);                                         \
    int   mt_ = (int)((mb_cur >> (SLOT_)) & 1);                               \
    int   tn_ = (T_) + 8; if (tn_ > SEQ - 1) tn_ = SEQ - 1;                   \
    embuf[SLOT_] = em[tn_ * NL + jc];                                         \
    unsigned cu_, du_, eu_, fu_;                                              \
    spread4(__float_as_uint(v), cu_, du_, eu_, fu_);                          \
    float c_ = __uint_as_float(cu_), d_ = __uint_as_float(du_);               \
    float e_ = __uint_as_float(eu_), f_ = __uint_as_float(fu_);               \
    float rm_ = 1.0f;                                                         \
    if (RN_) {                                                                \
        float g_ = fmaxf(fmaxf(c_, d_), fmaxf(e_, f_));                       \
        g_ = fmaxf(g_, rrf<8>(g_));  g_ = fmaxf(g_, rrf<4>(g_));              \
        g_ = fmaxf(g_, rrf<2>(g_));  g_ = fmaxf(g_, rrf<1>(g_));              \
        rm_ = __builtin_amdgcn_rcpf(g_);                                      \
        S += __logf(g_);                                                      \
    }                                                                         \
    float a0_ = 0.f, a1_ = 0.f, a2_ = 0.f;                                    \
    float a3_ = 0.f, a4_ = 0.f, a5_ = 0.f;                                    \
    RF3(0,  a0_, a1_, a2_)  RF3(1,  a3_, a4_, a5_)                            \
    RF3(2,  a0_, a1_, a2_)  RF3(3,  a3_, a4_, a5_)                            \
    RF3(4,  a0_, a1_, a2_)  RF3(5,  a3_, a4_, a5_)                            \
    RF3(6,  a0_, a1_, a2_)  RF3(7,  a3_, a4_, a5_)                            \
    RF3(8,  a0_, a1_, a2_)  RF3(9,  a3_, a4_, a5_)                            \
    RF3(10, a0_, a1_, a2_)  RF3(11, a3_, a4_, a5_)                            \
    RF3(12, a0_, a1_, a2_)  RF3(13, a3_, a4_, a5_)                            \
    RF3(14, a0_, a1_, a2_)  RF3(15, a3_, a4_, a5_)                            \
    if (useF) {   /* wave-uniform; never taken when f holds only junk */      \
        RFF(0,  a0_) RFF(1,  a1_) RFF(2,  a2_) RFF(3,  a3_)                   \
        RFF(4,  a4_) RFF(5,  a5_) RFF(6,  a0_) RFF(7,  a1_)                   \
        RFF(8,  a2_) RFF(9,  a3_) RFF(10, a4_) RFF(11, a5_)                   \
        RFF(12, a0_) RFF(13, a1_) RFF(14, a2_) RFF(15, a3_)                   \
    }                                                                         \
    float acc_ = ((a0_ + a3_) + (a1_ + a4_)) + (a2_ + a5_);                   \
    v = (mt_ ? acc_ * ee_ : v) * rm_;                                         \
} while (0)

// Coefficient prep: push the LANE INDEX through the same spread+rotate
// network; whatever value arrives at this lane via (stream, rotation N)
// gets coefficient exp(T[arrived_index][jc]) -- or 0 for out-of-range
// (junk-lane) indices.  Pairing is correct by construction, independent
// of the exact permlane/DPP direction semantics.
#define EPREP(N_) do {                                                        \
    unsigned i0 = rru<N_>(ic_), i1 = rru<N_>(id_);                            \
    unsigned i2 = rru<N_>(ie_), i3 = rru<N_>(if_);                            \
    EA[N_] = (i0 < (unsigned)NL) ? __expf(trans[i0 * NL + jc]) : 0.0f;        \
    EB[N_] = (i1 < (unsigned)NL) ? __expf(trans[i1 * NL + jc]) : 0.0f;        \
    EC[N_] = (i2 < (unsigned)NL) ? __expf(trans[i2 * NL + jc]) : 0.0f;        \
    ED[N_] = (i3 < (unsigned)NL) ? __expf(trans[i3 * NL + jc]) : 0.0f;        \
} while (0)

// Block = 128: wave 0 = forward recurrence (1 sequence), wave 1 = gold.
// 512 blocks -> 1 forward wave per SIMD on half the SIMDs; step chain
// latency is the whole game, so everything lives in the VALU.
__global__ __launch_bounds__(128)
__attribute__((amdgpu_waves_per_eu(1, 1)))
void crf_fused(
    const float* __restrict__ emissions, const int* __restrict__ labels,
    const int* __restrict__ mask, const float* __restrict__ trans,
    const float* __restrict__ startt, const float* __restrict__ endt,
    float* __restrict__ gold_out, float* __restrict__ fwd_out)
{
    const int b   = blockIdx.x;
    const int tid = threadIdx.x;
    const float* em = emissions + (size_t)b * SEQ * NL;
    const int*   mk = mask + b * SEQ;

    if (tid < 64) {
        // ---------------- wave 0: forward algorithm ----------------
        const int  j   = tid;                  // lanes 48..63 idle mirrors
        const bool act = (j < NL);
        const int  jc  = act ? j : NL - 1;

        // Index-tracked spread of the lane id -> per-(stream, rotation)
        // source indices, then coefficient tables EA..ED[16] in registers.
        unsigned ic_, id_, ie_, if_;
        spread4((unsigned)j, ic_, id_, ie_, if_);
        const bool useF = (__ballot(if_ < (unsigned)NL) != 0ull);

        float EA[16], EB[16], EC[16], ED[16];
        EPREP(0);  EPREP(1);  EPREP(2);  EPREP(3);
        EPREP(4);  EPREP(5);  EPREP(6);  EPREP(7);
        EPREP(8);  EPREP(9);  EPREP(10); EPREP(11);
        EPREP(12); EPREP(13); EPREP(14); EPREP(15);

        // mask ballots: one vector load + __ballot per 8-step block.
        int mval = mk[tid & 7];                          // steps 0..7 (bit 0 unused)
        unsigned long long mb_cur = __ballot(mval != 0);
        mval = mk[8 + (tid & 7)];                        // preload steps 8..15

        // init: score0 = start + emit[0]; normalize by wave max.
        float s0 = act ? (startt[jc] + em[jc]) : -3.0e38f;
        float m0 = s0;
        #pragma unroll
        for (int o = 32; o; o >>= 1) m0 = fmaxf(m0, __shfl_xor(m0, o));
        float v = act ? __expf(s0 - m0) : 0.0f;
        float S = m0;

        // 8-deep emission prefetch ring.
        float embuf[8];
        #pragma unroll
        for (int t = 1; t <= 8; ++t) embuf[t & 7] = em[t * NL + jc];

        // peeled steps 1..7; renorm at step 5 (v from step 4).
        CRF_STEP(1, 1, 0); CRF_STEP(2, 2, 0); CRF_STEP(3, 3, 0); CRF_STEP(4, 4, 0);
        CRF_STEP(5, 5, 1); CRF_STEP(6, 6, 0); CRF_STEP(7, 7, 0);

        // aligned chunks of 8: tb = 8,16,...,1016 covers t = 8..1023.
        // renorm at tb+0 and tb+4 -> every <=4 steps (fp32-safe growth).
        for (int tb = 8; tb <= SEQ - 8; tb += 8) {
            mb_cur = __ballot(mval != 0);                // mask bits for tb..tb+7
            int tm = tb + 8 + (tid & 7);                 // prefetch next block
            if (tm > SEQ - 1) tm = SEQ - 1;
            mval = mk[tm];
            CRF_STEP(tb + 0, 0, 1);
            CRF_STEP(tb + 1, 1, 0); CRF_STEP(tb + 2, 2, 0); CRF_STEP(tb + 3, 3, 0);
            CRF_STEP(tb + 4, 4, 1);
            CRF_STEP(tb + 5, 5, 0); CRF_STEP(tb + 6, 6, 0); CRF_STEP(tb + 7, 7, 0);
        }

        // fwd = S + log(sum_j v[j] * exp(end[j])) over active lanes.
        float w = act ? v * __expf(endt[jc]) : 0.0f;
        #pragma unroll
        for (int o = 32; o; o >>= 1) w += __shfl_xor(w, o);
        if (j == 0) fwd_out[b] = S + __logf(w);
    } else {
        // ---------------- wave 1: gold score ----------------
        const int l = tid - 64;
        const int* lb = labels + b * SEQ;

        float part = 0.0f; int mcnt = 0;
        for (int t = l; t < SEQ; t += 64) {
            int lt = lb[t];
            int mt = mk[t];
            mcnt += mt;
            if (t == 0) {
                part += startt[lt] + em[lt];
            } else {
                float e  = em[t * NL + lt];
                float tr = trans[lt * NL + lb[t - 1]];   // gold uses T[cur][prev]
                if (mt) part += e + tr;
            }
        }
        #pragma unroll
        for (int o = 32; o; o >>= 1) {
            part += __shfl_xor(part, o);
            mcnt += __shfl_xor(mcnt, o);
        }
        if (l == 0) {
            int len = mcnt - 1;
            gold_out[b] = part + endt[lb[len]];
        }
    }
}

__global__ __launch_bounds__(64) void crf_reduce(
    const float* __restrict__ gold, const float* __restrict__ fwd,
    float* __restrict__ out)
{
    const int l = threadIdx.x;
    float s = 0.0f;
    for (int bIdx = l; bIdx < BATCH; bIdx += 64) s += fwd[bIdx] - gold[bIdx];
    #pragma unroll
    for (int o = 32; o; o >>= 1) s += __shfl_xor(s, o);
    if (l == 0) out[0] = s * (1.0f / (float)BATCH);
}

extern "C" void kernel_launch(void* const* d_in, const int* in_sizes, int n_in,
                              void* d_out, int out_size, void* d_ws, size_t ws_size,
                              hipStream_t stream) {
    const float* emissions = (const float*)d_in[0];
    const int*   labels    = (const int*)d_in[1];
    const int*   mask      = (const int*)d_in[2];
    const float* trans     = (const float*)d_in[3];
    const float* startt    = (const float*)d_in[4];
    const float* endt      = (const float*)d_in[5];
    float*       out       = (float*)d_out;
    float*       wsf       = (float*)d_ws;   // [0..512) gold, [512..1024) fwd

    crf_fused<<<BATCH, 128, 0, stream>>>(emissions, labels, mask, trans, startt, endt,
                                         wsf, wsf + BATCH);
    crf_reduce<<<1, 64, 0, stream>>>(wsf, wsf + BATCH, out);
}

// Round 4
// 413.133 us; speedup vs baseline: 1.0978x; 1.0978x over previous
//
#include <hip/hip_runtime.h>

constexpr int NL    = 48;
constexpr int SEQ   = 1024;
constexpr int BATCH = 512;

// DPP row_ror:N (rotate within each 16-lane row) -- pure VALU cross-lane.
// Uses mov_dpp (NO tied-old operand, unlike update_dpp): compiles to a single
// v_mov_b32_dpp, and is eligible for GCNDPPCombine folding into the consuming
// v_fmac_f32 / v_max_f32 (DPP on VOP2 src0) -> v_fmac_f32_dpp.
// Round-3 lesson: update_dpp's tied old forced a v_mov + v_mov_dpp pair per
// rotation plus VALU->DPP hazard wait-states (~500 stall cy/step).
template<int N>
__device__ __forceinline__ float rrf(float x) {
    if constexpr (N == 0) return x;
    else return __int_as_float(
        __builtin_amdgcn_mov_dpp(__float_as_int(x), 0x120 | N, 0xF, 0xF, false));
}
template<int N>
__device__ __forceinline__ unsigned rru(unsigned x) {
    if constexpr (N == 0) return x;
    else return (unsigned)
        __builtin_amdgcn_mov_dpp((int)x, 0x120 | N, 0xF, 0xF, false);
}

// 3-op full-wave spread via gfx950 permlane swaps (VALU): from per-lane x
// produce 4 streams; across (stream, rotation 0..15) every original lane's
// value reaches every lane exactly once.  The exact permutation does NOT
// matter: coefficients are derived by pushing the lane index through this
// same network (EPREP), so pairing is correct by construction (verified in
// round 3: absmax 0.0 with this exact machinery).
__device__ __forceinline__ void spread4(unsigned x,
        unsigned &c, unsigned &d, unsigned &e, unsigned &f) {
    auto rA = __builtin_amdgcn_permlane32_swap(x, x, false, false);
    auto rc = __builtin_amdgcn_permlane16_swap(rA[0], rA[0], false, false);
    auto re = __builtin_amdgcn_permlane16_swap(rA[1], rA[1], false, false);
    c = rc[0]; d = rc[1]; e = re[0]; f = re[1];
}

// Rotation N of all 4 streams against the index-matched coefficient tables.
// Written exactly as a = fma(dpp(x), e, a) so the backend can select
// v_fmac_f32 and fold the DPP: one v_fmac_f32_dpp per MAC.  Junk slots
// (pushed index >= 48) have coefficient 0 -- always executed, never branch.
#define RF4(N_, x0_, x1_, x2_, x3_)                                           \
    x0_ = fmaf(rrf<N_>(c_), EA[N_], x0_);                                     \
    x1_ = fmaf(rrf<N_>(d_), EB[N_], x1_);                                     \
    x2_ = fmaf(rrf<N_>(e_), EC[N_], x2_);                                     \
    x3_ = fmaf(rrf<N_>(f_), ED[N_], x3_);

// One forward step, entirely in the VALU: 3 permlane + 64 fmac(+dpp).
// 8 accumulator chains (8-deep each; reissue spacing 16 cy >> 4 cy fmac
// latency) -> the FMA block is pure issue, ~130 cy.
// RN_: renorm max over the pre-step v taken from the spread streams (junk
// slots are exact duplicates of v[47] -- never affect the max), reduced by
// a 4-deep row_ror max butterfly (v_max_f32_dpp); rm_ folded into both mask
// paths; S += log(max).  Identical numerics to rounds 0-3.
#define CRF_STEP(T_, SLOT_, RN_) do {                                         \
    float ee_ = __expf(embuf[SLOT_]);                                         \
    int   mt_ = (int)((mb_cur >> (SLOT_)) & 1);                               \
    int   tn_ = (T_) + 8; if (tn_ > SEQ - 1) tn_ = SEQ - 1;                   \
    embuf[SLOT_] = em[tn_ * NL + jc];                                         \
    unsigned cu_, du_, eu_, fu_;                                              \
    spread4(__float_as_uint(v), cu_, du_, eu_, fu_);                          \
    float c_ = __uint_as_float(cu_), d_ = __uint_as_float(du_);               \
    float e_ = __uint_as_float(eu_), f_ = __uint_as_float(fu_);               \
    float rm_ = 1.0f;                                                         \
    if (RN_) {                                                                \
        float g_ = fmaxf(fmaxf(c_, d_), fmaxf(e_, f_));                       \
        g_ = fmaxf(g_, rrf<8>(g_));  g_ = fmaxf(g_, rrf<4>(g_));              \
        g_ = fmaxf(g_, rrf<2>(g_));  g_ = fmaxf(g_, rrf<1>(g_));              \
        rm_ = __builtin_amdgcn_rcpf(g_);                                      \
        S += __logf(g_);                                                      \
    }                                                                         \
    float a0_ = 0.f, a1_ = 0.f, a2_ = 0.f, a3_ = 0.f;                         \
    float a4_ = 0.f, a5_ = 0.f, a6_ = 0.f, a7_ = 0.f;                         \
    RF4(0,  a0_, a1_, a2_, a3_)  RF4(1,  a4_, a5_, a6_, a7_)                  \
    RF4(2,  a0_, a1_, a2_, a3_)  RF4(3,  a4_, a5_, a6_, a7_)                  \
    RF4(4,  a0_, a1_, a2_, a3_)  RF4(5,  a4_, a5_, a6_, a7_)                  \
    RF4(6,  a0_, a1_, a2_, a3_)  RF4(7,  a4_, a5_, a6_, a7_)                  \
    RF4(8,  a0_, a1_, a2_, a3_)  RF4(9,  a4_, a5_, a6_, a7_)                  \
    RF4(10, a0_, a1_, a2_, a3_)  RF4(11, a4_, a5_, a6_, a7_)                  \
    RF4(12, a0_, a1_, a2_, a3_)  RF4(13, a4_, a5_, a6_, a7_)                  \
    RF4(14, a0_, a1_, a2_, a3_)  RF4(15, a4_, a5_, a6_, a7_)                  \
    float acc_ = ((a0_ + a4_) + (a1_ + a5_)) + ((a2_ + a6_) + (a3_ + a7_));   \
    v = (mt_ ? acc_ * ee_ : v) * rm_;                                         \
} while (0)

// Coefficient prep: push the LANE INDEX through the same spread+rotate
// network; whatever value arrives at this lane via (stream, rotation N)
// gets coefficient exp(T[arrived_index][jc]) -- or 0 for out-of-range
// (junk-lane) indices.  Pairing correct by construction, independent of
// the exact permlane/DPP direction semantics.
#define EPREP(N_) do {                                                        \
    unsigned i0 = rru<N_>(ic_), i1 = rru<N_>(id_);                            \
    unsigned i2 = rru<N_>(ie_), i3 = rru<N_>(if_);                            \
    EA[N_] = (i0 < (unsigned)NL) ? __expf(trans[i0 * NL + jc]) : 0.0f;        \
    EB[N_] = (i1 < (unsigned)NL) ? __expf(trans[i1 * NL + jc]) : 0.0f;        \
    EC[N_] = (i2 < (unsigned)NL) ? __expf(trans[i2 * NL + jc]) : 0.0f;        \
    ED[N_] = (i3 < (unsigned)NL) ? __expf(trans[i3 * NL + jc]) : 0.0f;        \
} while (0)

// Block = 128: wave 0 = forward recurrence (1 sequence), wave 1 = gold.
// 512 blocks; per-step chain latency is the whole game, so everything
// lives in the VALU pipe.
__global__ __launch_bounds__(128)
__attribute__((amdgpu_waves_per_eu(1, 1)))
void crf_fused(
    const float* __restrict__ emissions, const int* __restrict__ labels,
    const int* __restrict__ mask, const float* __restrict__ trans,
    const float* __restrict__ startt, const float* __restrict__ endt,
    float* __restrict__ gold_out, float* __restrict__ fwd_out)
{
    const int b   = blockIdx.x;
    const int tid = threadIdx.x;
    const float* em = emissions + (size_t)b * SEQ * NL;
    const int*   mk = mask + b * SEQ;

    if (tid < 64) {
        // ---------------- wave 0: forward algorithm ----------------
        const int  j   = tid;                  // lanes 48..63 idle mirrors
        const bool act = (j < NL);
        const int  jc  = act ? j : NL - 1;

        // Index-tracked spread of the lane id -> per-(stream, rotation)
        // source indices, then coefficient tables EA..ED[16] in registers.
        unsigned ic_, id_, ie_, if_;
        spread4((unsigned)j, ic_, id_, ie_, if_);

        float EA[16], EB[16], EC[16], ED[16];
        EPREP(0);  EPREP(1);  EPREP(2);  EPREP(3);
        EPREP(4);  EPREP(5);  EPREP(6);  EPREP(7);
        EPREP(8);  EPREP(9);  EPREP(10); EPREP(11);
        EPREP(12); EPREP(13); EPREP(14); EPREP(15);

        // mask ballots: one vector load + __ballot per 8-step block.
        int mval = mk[tid & 7];                          // steps 0..7 (bit 0 unused)
        unsigned long long mb_cur = __ballot(mval != 0);
        mval = mk[8 + (tid & 7)];                        // preload steps 8..15

        // init: score0 = start + emit[0]; normalize by wave max.
        float s0 = act ? (startt[jc] + em[jc]) : -3.0e38f;
        float m0 = s0;
        #pragma unroll
        for (int o = 32; o; o >>= 1) m0 = fmaxf(m0, __shfl_xor(m0, o));
        float v = act ? __expf(s0 - m0) : 0.0f;
        float S = m0;

        // 8-deep emission prefetch ring.
        float embuf[8];
        #pragma unroll
        for (int t = 1; t <= 8; ++t) embuf[t & 7] = em[t * NL + jc];

        // peeled steps 1..7; renorm at step 5 (v from step 4).
        CRF_STEP(1, 1, 0); CRF_STEP(2, 2, 0); CRF_STEP(3, 3, 0); CRF_STEP(4, 4, 0);
        CRF_STEP(5, 5, 1); CRF_STEP(6, 6, 0); CRF_STEP(7, 7, 0);

        // aligned chunks of 8: tb = 8,16,...,1016 covers t = 8..1023.
        // renorm at tb+0 and tb+4 -> every <=4 steps (fp32-safe growth).
        for (int tb = 8; tb <= SEQ - 8; tb += 8) {
            mb_cur = __ballot(mval != 0);                // mask bits for tb..tb+7
            int tm = tb + 8 + (tid & 7);                 // prefetch next block
            if (tm > SEQ - 1) tm = SEQ - 1;
            mval = mk[tm];
            CRF_STEP(tb + 0, 0, 1);
            CRF_STEP(tb + 1, 1, 0); CRF_STEP(tb + 2, 2, 0); CRF_STEP(tb + 3, 3, 0);
            CRF_STEP(tb + 4, 4, 1);
            CRF_STEP(tb + 5, 5, 0); CRF_STEP(tb + 6, 6, 0); CRF_STEP(tb + 7, 7, 0);
        }

        // fwd = S + log(sum_j v[j] * exp(end[j])) over active lanes.
        float w = act ? v * __expf(endt[jc]) : 0.0f;
        #pragma unroll
        for (int o = 32; o; o >>= 1) w += __shfl_xor(w, o);
        if (j == 0) fwd_out[b] = S + __logf(w);
    } else {
        // ---------------- wave 1: gold score ----------------
        const int l = tid - 64;
        const int* lb = labels + b * SEQ;

        float part = 0.0f; int mcnt = 0;
        for (int t = l; t < SEQ; t += 64) {
            int lt = lb[t];
            int mt = mk[t];
            mcnt += mt;
            if (t == 0) {
                part += startt[lt] + em[lt];
            } else {
                float e  = em[t * NL + lt];
                float tr = trans[lt * NL + lb[t - 1]];   // gold uses T[cur][prev]
                if (mt) part += e + tr;
            }
        }
        #pragma unroll
        for (int o = 32; o; o >>= 1) {
            part += __shfl_xor(part, o);
            mcnt += __shfl_xor(mcnt, o);
        }
        if (l == 0) {
            int len = mcnt - 1;
            gold_out[b] = part + endt[lb[len]];
        }
    }
}

__global__ __launch_bounds__(64) void crf_reduce(
    const float* __restrict__ gold, const float* __restrict__ fwd,
    float* __restrict__ out)
{
    const int l = threadIdx.x;
    float s = 0.0f;
    for (int bIdx = l; bIdx < BATCH; bIdx += 64) s += fwd[bIdx] - gold[bIdx];
    #pragma unroll
    for (int o = 32; o; o >>= 1) s += __shfl_xor(s, o);
    if (l == 0) out[0] = s * (1.0f / (float)BATCH);
}

extern "C" void kernel_launch(void* const* d_in, const int* in_sizes, int n_in,
                              void* d_out, int out_size, void* d_ws, size_t ws_size,
                              hipStream_t stream) {
    const float* emissions = (const float*)d_in[0];
    const int*   labels    = (const int*)d_in[1];
    const int*   mask      = (const int*)d_in[2];
    const float* trans     = (const float*)d_in[3];
    const float* startt    = (const float*)d_in[4];
    const float* endt      = (const float*)d_in[5];
    float*       out       = (float*)d_out;
    float*       wsf       = (float*)d_ws;   // [0..512) gold, [512..1024) fwd

    crf_fused<<<BATCH, 128, 0, stream>>>(emissions, labels, mask, trans, startt, endt,
                                         wsf, wsf + BATCH);
    crf_reduce<<<1, 64, 0, stream>>>(wsf, wsf + BATCH, out);
}

// Round 5
// 361.413 us; speedup vs baseline: 1.2549x; 1.1431x over previous
//
#include <hip/hip_runtime.h>

constexpr int NL    = 48;
constexpr int SEQ   = 1024;
constexpr int BATCH = 512;

// ---------------------------------------------------------------------------
// Rotation via builtin mov_dpp (compiler-managed hazards) -- used for the
// one-time index tracking (EPREP) and the amortized renorm butterfly.
template<int N>
__device__ __forceinline__ float rrf(float x) {
    if constexpr (N == 0) return x;
    else return __int_as_float(
        __builtin_amdgcn_mov_dpp(__float_as_int(x), 0x120 | N, 0xF, 0xF, false));
}
template<int N>
__device__ __forceinline__ unsigned rru(unsigned x) {
    if constexpr (N == 0) return x;
    else return (unsigned)
        __builtin_amdgcn_mov_dpp((int)x, 0x120 | N, 0xF, 0xF, false);
}

// Fused rotate-and-MAC: ONE v_fmac_f32_dpp (DPP rides src0 of VOP2).
// Round-4 lesson: the compiler selects VOP3 v_fma_f32 (no DPP possible) and
// leaves v_mov_b32_dpp unfused -> 2 instrs/MAC; inline asm guarantees 1.
// Same dpp_ctrl (row_ror:N), row_mask:0xf, bank_mask:0xf as rru<N>/rrf<N>,
// so EPREP's index tracking pairs coefficients correctly by construction.
#define FMAC_DPP(ACC_, SRC_, COEF_, N_)                                       \
    asm("v_fmac_f32_dpp %0, %1, %2 row_ror:" #N_                              \
        " row_mask:0xf bank_mask:0xf"                                         \
        : "+v"(ACC_) : "v"(SRC_), "v"(COEF_))

// 3-op full-wave spread via gfx950 permlane swaps (VALU).  Across
// (stream, rotation 0..15) every original lane's value reaches every lane
// exactly once (proven by r3/r4: absmax 0.0 with zero-coeff junk slots).
__device__ __forceinline__ void spread4(unsigned x,
        unsigned &c, unsigned &d, unsigned &e, unsigned &f) {
    auto rA = __builtin_amdgcn_permlane32_swap(x, x, false, false);
    auto rc = __builtin_amdgcn_permlane16_swap(rA[0], rA[0], false, false);
    auto re = __builtin_amdgcn_permlane16_swap(rA[1], rA[1], false, false);
    c = rc[0]; d = rc[1]; e = re[0]; f = re[1];
}

// Rotation N of streams c,d,e into 6 accumulator chains (literal N so the
// nested # stringization in FMAC_DPP sees the digit).
#define RF3A(N_, x0_, x1_, x2_)                                               \
    FMAC_DPP(x0_, c_, EA[N_], N_);                                            \
    FMAC_DPP(x1_, d_, EB[N_], N_);                                            \
    FMAC_DPP(x2_, e_, EC[N_], N_);
// Fallback stream-f MAC (builtin mov + fma; only taken if useF).
#define RFF(N_, xx_) xx_ = fmaf(rrf<N_>(f_), ED[N_], xx_);

// One forward step, entirely in the VALU: 3 permlane + s_nop + 48 fmac(+dpp).
// RN_: renorm max over the pre-step v taken from the spread streams, reduced
// by a 4-deep row_ror max butterfly; rm_ = rcp(max) folded into both mask
// paths (exact identity for any positive finite m); S += log(max).
#define CRF_STEP(T_, SLOT_, RN_) do {                                         \
    float ee_ = __expf(embuf[SLOT_]);                                         \
    int   mt_ = (int)((mb_cur >> (SLOT_)) & 1);                               \
    int   tn_ = (T_) + 8; if (tn_ > SEQ - 1) tn_ = SEQ - 1;                   \
    embuf[SLOT_] = em[tn_ * NL + jc];                                         \
    unsigned cu_, du_, eu_, fu_;                                              \
    spread4(__float_as_uint(v), cu_, du_, eu_, fu_);                          \
    /* >=2 wait states between the permlane writes and the first inline-asm  \
       DPP read of c_/d_/e_ (asm bypasses the compiler hazard recognizer) */ \
    asm("s_nop 1" : "+v"(cu_), "+v"(du_), "+v"(eu_));                         \
    float c_ = __uint_as_float(cu_), d_ = __uint_as_float(du_);               \
    float e_ = __uint_as_float(eu_), f_ = __uint_as_float(fu_);               \
    float rm_ = 1.0f;                                                         \
    if (RN_) {                                                                \
        float g_ = fmaxf(fmaxf(c_, d_), fmaxf(e_, f_));                       \
        g_ = fmaxf(g_, rrf<8>(g_));  g_ = fmaxf(g_, rrf<4>(g_));              \
        g_ = fmaxf(g_, rrf<2>(g_));  g_ = fmaxf(g_, rrf<1>(g_));              \
        rm_ = __builtin_amdgcn_rcpf(g_);                                      \
        S += __logf(g_);                                                      \
    }                                                                         \
    float a0_ = c_ * EA[0], a1_ = d_ * EB[0], a2_ = e_ * EC[0];               \
    float a3_ = 0.f, a4_ = 0.f, a5_ = 0.f;                                    \
    RF3A(1,  a3_, a4_, a5_)  RF3A(2,  a0_, a1_, a2_)                          \
    RF3A(3,  a3_, a4_, a5_)  RF3A(4,  a0_, a1_, a2_)                          \
    RF3A(5,  a3_, a4_, a5_)  RF3A(6,  a0_, a1_, a2_)                          \
    RF3A(7,  a3_, a4_, a5_)  RF3A(8,  a0_, a1_, a2_)                          \
    RF3A(9,  a3_, a4_, a5_)  RF3A(10, a0_, a1_, a2_)                          \
    RF3A(11, a3_, a4_, a5_)  RF3A(12, a0_, a1_, a2_)                          \
    RF3A(13, a3_, a4_, a5_)  RF3A(14, a0_, a1_, a2_)                          \
    RF3A(15, a3_, a4_, a5_)                                                   \
    if (useF) {   /* wave-uniform; taken only if stream f carries real idx */ \
        RFF(0,  a0_) RFF(1,  a1_) RFF(2,  a2_) RFF(3,  a3_)                   \
        RFF(4,  a4_) RFF(5,  a5_) RFF(6,  a0_) RFF(7,  a1_)                   \
        RFF(8,  a2_) RFF(9,  a3_) RFF(10, a4_) RFF(11, a5_)                   \
        RFF(12, a0_) RFF(13, a1_) RFF(14, a2_) RFF(15, a3_)                   \
    }                                                                         \
    float acc_ = ((a0_ + a3_) + (a1_ + a4_)) + (a2_ + a5_);                   \
    v = (mt_ ? acc_ * ee_ : v) * rm_;                                         \
} while (0)

// Coefficient prep: push the LANE INDEX through the same spread+rotate
// network; whatever value arrives at this lane via (stream, rotation N)
// gets coefficient exp(T[arrived_index][jc]) -- or 0 for out-of-range
// (junk) indices.  Pairing correct by construction, independent of the
// exact permlane/DPP direction semantics.
#define EPREP(N_) do {                                                        \
    unsigned i0 = rru<N_>(ic_), i1 = rru<N_>(id_);                            \
    unsigned i2 = rru<N_>(ie_), i3 = rru<N_>(if_);                            \
    EA[N_] = (i0 < (unsigned)NL) ? __expf(trans[i0 * NL + jc]) : 0.0f;        \
    EB[N_] = (i1 < (unsigned)NL) ? __expf(trans[i1 * NL + jc]) : 0.0f;        \
    EC[N_] = (i2 < (unsigned)NL) ? __expf(trans[i2 * NL + jc]) : 0.0f;        \
    ED[N_] = (i3 < (unsigned)NL) ? __expf(trans[i3 * NL + jc]) : 0.0f;        \
} while (0)

// Block = 128: wave 0 = forward recurrence (1 sequence), wave 1 = gold.
// 512 blocks; a solo wave issues at ~1 instr/5cy, so wall time ~= steps x
// instrs x 5cy -- instruction count per step is the whole game.
__global__ __launch_bounds__(128)
__attribute__((amdgpu_waves_per_eu(1, 1)))
void crf_fused(
    const float* __restrict__ emissions, const int* __restrict__ labels,
    const int* __restrict__ mask, const float* __restrict__ trans,
    const float* __restrict__ startt, const float* __restrict__ endt,
    float* __restrict__ gold_out, float* __restrict__ fwd_out)
{
    const int b   = blockIdx.x;
    const int tid = threadIdx.x;
    const float* em = emissions + (size_t)b * SEQ * NL;
    const int*   mk = mask + b * SEQ;

    if (tid < 64) {
        // ---------------- wave 0: forward algorithm ----------------
        const int  j   = tid;                  // lanes 48..63 idle mirrors
        const bool act = (j < NL);
        const int  jc  = act ? j : NL - 1;

        // Index-tracked spread of the lane id -> per-(stream, rotation)
        // source indices, then coefficient tables EA..ED[16] in registers.
        unsigned ic_, id_, ie_, if_;
        spread4((unsigned)j, ic_, id_, ie_, if_);
        // row_ror permutes within the row's value set, so checking the
        // unrotated f-slots covers all 16 rotations of stream f.
        const bool useF = (__ballot(if_ < (unsigned)NL) != 0ull);

        float EA[16], EB[16], EC[16], ED[16];
        EPREP(0);  EPREP(1);  EPREP(2);  EPREP(3);
        EPREP(4);  EPREP(5);  EPREP(6);  EPREP(7);
        EPREP(8);  EPREP(9);  EPREP(10); EPREP(11);
        EPREP(12); EPREP(13); EPREP(14); EPREP(15);

        // mask ballots: one vector load + __ballot per 8-step block.
        int mval = mk[tid & 7];                          // steps 0..7 (bit 0 unused)
        unsigned long long mb_cur = __ballot(mval != 0);
        mval = mk[8 + (tid & 7)];                        // preload steps 8..15

        // init: score0 = start + emit[0]; normalize by wave max.
        float s0 = act ? (startt[jc] + em[jc]) : -3.0e38f;
        float m0 = s0;
        #pragma unroll
        for (int o = 32; o; o >>= 1) m0 = fmaxf(m0, __shfl_xor(m0, o));
        float v = act ? __expf(s0 - m0) : 0.0f;
        float S = m0;

        // 8-deep emission prefetch ring.
        float embuf[8];
        #pragma unroll
        for (int t = 1; t <= 8; ++t) embuf[t & 7] = em[t * NL + jc];

        // peeled steps 1..7; renorm at step 5 (v from step 4).
        CRF_STEP(1, 1, 0); CRF_STEP(2, 2, 0); CRF_STEP(3, 3, 0); CRF_STEP(4, 4, 0);
        CRF_STEP(5, 5, 1); CRF_STEP(6, 6, 0); CRF_STEP(7, 7, 0);

        // aligned chunks of 8: tb = 8,16,...,1016 covers t = 8..1023.
        // renorm at tb+0 and tb+4 -> every <=4 steps (fp32-safe growth).
        for (int tb = 8; tb <= SEQ - 8; tb += 8) {
            mb_cur = __ballot(mval != 0);                // mask bits for tb..tb+7
            int tm = tb + 8 + (tid & 7);                 // prefetch next block
            if (tm > SEQ - 1) tm = SEQ - 1;
            mval = mk[tm];
            CRF_STEP(tb + 0, 0, 1);
            CRF_STEP(tb + 1, 1, 0); CRF_STEP(tb + 2, 2, 0); CRF_STEP(tb + 3, 3, 0);
            CRF_STEP(tb + 4, 4, 1);
            CRF_STEP(tb + 5, 5, 0); CRF_STEP(tb + 6, 6, 0); CRF_STEP(tb + 7, 7, 0);
        }

        // fwd = S + log(sum_j v[j] * exp(end[j])) over active lanes.
        float w = act ? v * __expf(endt[jc]) : 0.0f;
        #pragma unroll
        for (int o = 32; o; o >>= 1) w += __shfl_xor(w, o);
        if (j == 0) fwd_out[b] = S + __logf(w);
    } else {
        // ---------------- wave 1: gold score ----------------
        const int l = tid - 64;
        const int* lb = labels + b * SEQ;

        float part = 0.0f; int mcnt = 0;
        for (int t = l; t < SEQ; t += 64) {
            int lt = lb[t];
            int mt = mk[t];
            mcnt += mt;
            if (t == 0) {
                part += startt[lt] + em[lt];
            } else {
                float e  = em[t * NL + lt];
                float tr = trans[lt * NL + lb[t - 1]];   // gold uses T[cur][prev]
                if (mt) part += e + tr;
            }
        }
        #pragma unroll
        for (int o = 32; o; o >>= 1) {
            part += __shfl_xor(part, o);
            mcnt += __shfl_xor(mcnt, o);
        }
        if (l == 0) {
            int len = mcnt - 1;
            gold_out[b] = part + endt[lb[len]];
        }
    }
}

__global__ __launch_bounds__(64) void crf_reduce(
    const float* __restrict__ gold, const float* __restrict__ fwd,
    float* __restrict__ out)
{
    const int l = threadIdx.x;
    float s = 0.0f;
    for (int bIdx = l; bIdx < BATCH; bIdx += 64) s += fwd[bIdx] - gold[bIdx];
    #pragma unroll
    for (int o = 32; o; o >>= 1) s += __shfl_xor(s, o);
    if (l == 0) out[0] = s * (1.0f / (float)BATCH);
}

extern "C" void kernel_launch(void* const* d_in, const int* in_sizes, int n_in,
                              void* d_out, int out_size, void* d_ws, size_t ws_size,
                              hipStream_t stream) {
    const float* emissions = (const float*)d_in[0];
    const int*   labels    = (const int*)d_in[1];
    const int*   mask      = (const int*)d_in[2];
    const float* trans     = (const float*)d_in[3];
    const float* startt    = (const float*)d_in[4];
    const float* endt      = (const float*)d_in[5];
    float*       out       = (float*)d_out;
    float*       wsf       = (float*)d_ws;   // [0..512) gold, [512..1024) fwd

    crf_fused<<<BATCH, 128, 0, stream>>>(emissions, labels, mask, trans, startt, endt,
                                         wsf, wsf + BATCH);
    crf_reduce<<<1, 64, 0, stream>>>(wsf, wsf + BATCH, out);
}

// Round 6
// 349.101 us; speedup vs baseline: 1.2991x; 1.0353x over previous
//
#include <hip/hip_runtime.h>

constexpr int NL    = 48;
constexpr int SEQ   = 1024;
constexpr int BATCH = 512;

// ---------------------------------------------------------------------------
// Rotation via builtin mov_dpp (compiler-managed hazards) -- used for the
// one-time index tracking (EPREP) and the amortized renorm butterfly.
template<int N>
__device__ __forceinline__ float rrf(float x) {
    if constexpr (N == 0) return x;
    else return __int_as_float(
        __builtin_amdgcn_mov_dpp(__float_as_int(x), 0x120 | N, 0xF, 0xF, false));
}
template<int N>
__device__ __forceinline__ unsigned rru(unsigned x) {
    if constexpr (N == 0) return x;
    else return (unsigned)
        __builtin_amdgcn_mov_dpp((int)x, 0x120 | N, 0xF, 0xF, false);
}

// Fused rotate-and-MAC: ONE v_fmac_f32_dpp (DPP rides src0 of VOP2).
// Same dpp_ctrl (row_ror:N), row_mask:0xf, bank_mask:0xf as rru<N>, so the
// index-tracked EPREP pairs coefficients correctly by construction.
#define FMAC_DPP(ACC_, SRC_, COEF_, N_)                                       \
    asm("v_fmac_f32_dpp %0, %1, %2 row_ror:" #N_                              \
        " row_mask:0xf bank_mask:0xf"                                         \
        : "+v"(ACC_) : "v"(SRC_), "v"(COEF_))

// 3-op full-wave spread via gfx950 permlane swaps (VALU).  Across
// (stream, rotation 0..15) every original lane's value reaches every lane
// exactly once (proven r3-r5: absmax 0.0 with zero-coeff junk slots).
__device__ __forceinline__ void spread4(unsigned x,
        unsigned &c, unsigned &d, unsigned &e, unsigned &f) {
    auto rA = __builtin_amdgcn_permlane32_swap(x, x, false, false);
    auto rc = __builtin_amdgcn_permlane16_swap(rA[0], rA[0], false, false);
    auto re = __builtin_amdgcn_permlane16_swap(rA[1], rA[1], false, false);
    c = rc[0]; d = rc[1]; e = re[0]; f = re[1];
}

#define RF3A(N_, x0_, x1_, x2_)                                               \
    FMAC_DPP(x0_, c_, EA[N_], N_);                                            \
    FMAC_DPP(x1_, d_, EB[N_], N_);                                            \
    FMAC_DPP(x2_, e_, EC[N_], N_);

// One forward step: 3 permlane + 48 fmac(+dpp) when sigma killed stream f
// (useF false); fallback adds a 16-instr fused f-block.  PF_: prefetch
// em[t+8] via bumped pointer + compile-time immediate offset (no per-step
// address VALU, no clamps -- last block is peeled with PF_=0).
// RN_: renorm max over pre-step v from streams c,d,e (all 48 real states
// present there in the sigma layout; junk slots mirror state 47 / carry 0
// -- never affect the max), 4-deep row_ror max butterfly; rm_=rcp(max)
// folded into both mask paths; S += log(max).  Numerics identical r0-r5.
#define CRF_STEP(SLOT_, RN_, PF_) do {                                        \
    float ee_ = __expf(embuf[SLOT_]);                                         \
    int   mt_ = (int)((mb_cur >> (SLOT_)) & 1);                               \
    if (PF_) embuf[SLOT_] = emp[(8 + SLOT_) * NL];                            \
    unsigned cu_, du_, eu_, fu_;                                              \
    spread4(__float_as_uint(v), cu_, du_, eu_, fu_);                          \
    /* >=2 wait states between permlane writes and first asm DPP read */     \
    asm("s_nop 1" : "+v"(cu_), "+v"(du_), "+v"(eu_));                         \
    float c_ = __uint_as_float(cu_), d_ = __uint_as_float(du_);               \
    float e_ = __uint_as_float(eu_), f_ = __uint_as_float(fu_);               \
    float rm_ = 1.0f;                                                         \
    if (RN_) {                                                                \
        float g_ = fmaxf(fmaxf(c_, d_), e_);                                  \
        g_ = fmaxf(g_, rrf<8>(g_));  g_ = fmaxf(g_, rrf<4>(g_));              \
        g_ = fmaxf(g_, rrf<2>(g_));  g_ = fmaxf(g_, rrf<1>(g_));              \
        rm_ = __builtin_amdgcn_rcpf(g_);                                      \
        S += __logf(g_);                                                      \
    }                                                                         \
    float a0_ = c_ * EA[0], a1_ = d_ * EB[0], a2_ = e_ * EC[0];               \
    float a3_ = 0.f, a4_ = 0.f, a5_ = 0.f;                                    \
    RF3A(1,  a3_, a4_, a5_)  RF3A(2,  a0_, a1_, a2_)                          \
    RF3A(3,  a3_, a4_, a5_)  RF3A(4,  a0_, a1_, a2_)                          \
    RF3A(5,  a3_, a4_, a5_)  RF3A(6,  a0_, a1_, a2_)                          \
    RF3A(7,  a3_, a4_, a5_)  RF3A(8,  a0_, a1_, a2_)                          \
    RF3A(9,  a3_, a4_, a5_)  RF3A(10, a0_, a1_, a2_)                          \
    RF3A(11, a3_, a4_, a5_)  RF3A(12, a0_, a1_, a2_)                          \
    RF3A(13, a3_, a4_, a5_)  RF3A(14, a0_, a1_, a2_)                          \
    RF3A(15, a3_, a4_, a5_)                                                   \
    if (useF) {   /* wave-uniform; dead when sigma killed stream f */         \
        a3_ = fmaf(f_, ED[0], a3_);                                           \
        FMAC_DPP(a4_, f_, ED[1],  1);  FMAC_DPP(a5_, f_, ED[2],  2);          \
        FMAC_DPP(a0_, f_, ED[3],  3);  FMAC_DPP(a1_, f_, ED[4],  4);          \
        FMAC_DPP(a2_, f_, ED[5],  5);  FMAC_DPP(a3_, f_, ED[6],  6);          \
        FMAC_DPP(a4_, f_, ED[7],  7);  FMAC_DPP(a5_, f_, ED[8],  8);          \
        FMAC_DPP(a0_, f_, ED[9],  9);  FMAC_DPP(a1_, f_, ED[10], 10);         \
        FMAC_DPP(a2_, f_, ED[11], 11); FMAC_DPP(a3_, f_, ED[12], 12);         \
        FMAC_DPP(a4_, f_, ED[13], 13); FMAC_DPP(a5_, f_, ED[14], 14);         \
        FMAC_DPP(a0_, f_, ED[15], 15);                                        \
    }                                                                         \
    float acc_ = ((a0_ + a3_) + (a1_ + a4_)) + (a2_ + a5_);                   \
    v = (mt_ ? acc_ * ee_ : v) * rm_;                                         \
} while (0)

// Coefficient prep: push the PER-LANE STATE ID (sigma) through the same
// spread+rotate network; whatever state arrives at this lane via
// (stream, rotation N) gets coefficient exp(T[state][jc]) -- or 0 for junk
// states (>=48).  Pairing correct by construction for any HW semantics.
#define EPREP(N_) do {                                                        \
    unsigned i0 = rru<N_>(ic_), i1 = rru<N_>(id_);                            \
    unsigned i2 = rru<N_>(ie_), i3 = rru<N_>(if_);                            \
    EA[N_] = (i0 < (unsigned)NL) ? __expf(trans[i0 * NL + jc]) : 0.0f;        \
    EB[N_] = (i1 < (unsigned)NL) ? __expf(trans[i1 * NL + jc]) : 0.0f;        \
    EC[N_] = (i2 < (unsigned)NL) ? __expf(trans[i2 * NL + jc]) : 0.0f;        \
    ED[N_] = (i3 < (unsigned)NL) ? __expf(trans[i3 * NL + jc]) : 0.0f;        \
} while (0)

// Block = 128: wave 0 = forward recurrence (1 sequence), wave 1 = gold.
// Solo wave issues at ~3.8 cy/instr (r3/r4/r5 fit), so wall time ~=
// steps x (3.8 x instrs + ~208); instruction count per step is the game.
__global__ __launch_bounds__(128)
__attribute__((amdgpu_waves_per_eu(1, 1)))
void crf_fused(
    const float* __restrict__ emissions, const int* __restrict__ labels,
    const int* __restrict__ mask, const float* __restrict__ trans,
    const float* __restrict__ startt, const float* __restrict__ endt,
    float* __restrict__ gold_out, float* __restrict__ fwd_out)
{
    const int b   = blockIdx.x;
    const int tid = threadIdx.x;
    const float* em = emissions + (size_t)b * SEQ * NL;
    const int*   mk = mask + b * SEQ;

    // setup-only scratch for wave 0 (no barriers; single-wave producer and
    // consumer, DS in-order per wave).
    __shared__ int gflag[64];

    if (tid < 64) {
        // ---------------- wave 0: forward algorithm ----------------
        const int j = tid;

        // --- discover which source lanes feed stream f (set G) ---
        unsigned p0_, p1_, p2_, pf_;
        spread4((unsigned)j, p0_, p1_, p2_, pf_);
        gflag[j] = 0;
        gflag[pf_ & 63] = 1;                 // scatter-mark G members
        const int inG = gflag[j];
        const unsigned long long gball = __ballot(inG != 0);
        const int gcount = __popcll(gball);
        const unsigned long long below = (j == 0) ? 0ull : ((~0ull) >> (64 - j));

        // --- sigma: junk states (>=48) onto G; real states 0..47 onto the
        // rest (by lane rank).  Valid iff |G| <= 16; else identity. ---
        unsigned sig;
        if (gcount <= 16)
            sig = inG ? 48u + (unsigned)__popcll(gball & below)
                      : (unsigned)__popcll(~gball & below);
        else
            sig = (unsigned)j;

        const bool act = (sig < (unsigned)NL);
        const int  jc  = act ? (int)sig : NL - 1;

        // index-tracked spread of the STATE id; useF is ground truth
        // (false by construction when sigma succeeded).
        unsigned ic_, id_, ie_, if_;
        spread4(sig, ic_, id_, ie_, if_);
        const bool useF = (__ballot(if_ < (unsigned)NL) != 0ull);

        float EA[16], EB[16], EC[16], ED[16];
        EPREP(0);  EPREP(1);  EPREP(2);  EPREP(3);
        EPREP(4);  EPREP(5);  EPREP(6);  EPREP(7);
        EPREP(8);  EPREP(9);  EPREP(10); EPREP(11);
        EPREP(12); EPREP(13); EPREP(14); EPREP(15);

        // mask ballots: one vector load + __ballot per 8-step block.
        int mval = mk[tid & 7];                          // steps 0..7 (bit 0 unused)
        unsigned long long mb_cur = __ballot(mval != 0);
        mval = mk[8 + (tid & 7)];                        // preload steps 8..15

        // init: score0 = start + emit[0]; normalize by wave max.
        float s0 = act ? (startt[jc] + em[jc]) : -3.0e38f;
        float m0 = s0;
        #pragma unroll
        for (int o = 32; o; o >>= 1) m0 = fmaxf(m0, __shfl_xor(m0, o));
        float v = act ? __expf(s0 - m0) : 0.0f;
        float S = m0;

        // 8-deep emission prefetch ring; emp bumped by 8 rows per block so
        // in-loop loads use compile-time immediate offsets only.
        const float* emp = em + jc;
        float embuf[8];
        #pragma unroll
        for (int t = 1; t <= 8; ++t) embuf[t & 7] = emp[t * NL];

        // peeled steps 1..7 (block tb=0); renorm at step 5 (v from step 4).
        CRF_STEP(1, 0, 1); CRF_STEP(2, 0, 1); CRF_STEP(3, 0, 1); CRF_STEP(4, 0, 1);
        CRF_STEP(5, 1, 1); CRF_STEP(6, 0, 1); CRF_STEP(7, 0, 1);
        emp += 8 * NL;

        // main blocks tb = 8..1008: prefetch t+8 (max t+8 = 1023, no clamp).
        // renorm at tb+0 and tb+4 -> every <=4 steps (fp32-safe growth).
        for (int tb = 8; tb <= SEQ - 16; tb += 8) {
            mb_cur = __ballot(mval != 0);                // mask bits tb..tb+7
            mval = mk[tb + 8 + (tid & 7)];               // prefetch next block
            CRF_STEP(0, 1, 1);
            CRF_STEP(1, 0, 1); CRF_STEP(2, 0, 1); CRF_STEP(3, 0, 1);
            CRF_STEP(4, 1, 1);
            CRF_STEP(5, 0, 1); CRF_STEP(6, 0, 1); CRF_STEP(7, 0, 1);
            emp += 8 * NL;
        }

        // peeled last block t = 1016..1023: ring already full, no prefetch.
        mb_cur = __ballot(mval != 0);
        CRF_STEP(0, 1, 0);
        CRF_STEP(1, 0, 0); CRF_STEP(2, 0, 0); CRF_STEP(3, 0, 0);
        CRF_STEP(4, 1, 0);
        CRF_STEP(5, 0, 0); CRF_STEP(6, 0, 0); CRF_STEP(7, 0, 0);

        // fwd = S + log(sum_j v[j] * exp(end[j])) over active lanes.
        float w = act ? v * __expf(endt[jc]) : 0.0f;
        #pragma unroll
        for (int o = 32; o; o >>= 1) w += __shfl_xor(w, o);
        if (j == 0) fwd_out[b] = S + __logf(w);
    } else {
        // ---------------- wave 1: gold score ----------------
        const int l = tid - 64;
        const int* lb = labels + b * SEQ;

        float part = 0.0f; int mcnt = 0;
        for (int t = l; t < SEQ; t += 64) {
            int lt = lb[t];
            int mt = mk[t];
            mcnt += mt;
            if (t == 0) {
                part += startt[lt] + em[lt];
            } else {
                float e  = em[t * NL + lt];
                float tr = trans[lt * NL + lb[t - 1]];   // gold uses T[cur][prev]
                if (mt) part += e + tr;
            }
        }
        #pragma unroll
        for (int o = 32; o; o >>= 1) {
            part += __shfl_xor(part, o);
            mcnt += __shfl_xor(mcnt, o);
        }
        if (l == 0) {
            int len = mcnt - 1;
            gold_out[b] = part + endt[lb[len]];
        }
    }
}

__global__ __launch_bounds__(64) void crf_reduce(
    const float* __restrict__ gold, const float* __restrict__ fwd,
    float* __restrict__ out)
{
    const int l = threadIdx.x;
    float s = 0.0f;
    for (int bIdx = l; bIdx < BATCH; bIdx += 64) s += fwd[bIdx] - gold[bIdx];
    #pragma unroll
    for (int o = 32; o; o >>= 1) s += __shfl_xor(s, o);
    if (l == 0) out[0] = s * (1.0f / (float)BATCH);
}

extern "C" void kernel_launch(void* const* d_in, const int* in_sizes, int n_in,
                              void* d_out, int out_size, void* d_ws, size_t ws_size,
                              hipStream_t stream) {
    const float* emissions = (const float*)d_in[0];
    const int*   labels    = (const int*)d_in[1];
    const int*   mask      = (const int*)d_in[2];
    const float* trans     = (const float*)d_in[3];
    const float* startt    = (const float*)d_in[4];
    const float* endt      = (const float*)d_in[5];
    float*       out       = (float*)d_out;
    float*       wsf       = (float*)d_ws;   // [0..512) gold, [512..1024) fwd

    crf_fused<<<BATCH, 128, 0, stream>>>(emissions, labels, mask, trans, startt, endt,
                                         wsf, wsf + BATCH);
    crf_reduce<<<1, 64, 0, stream>>>(wsf, wsf + BATCH, out);
}